// Round 1
// baseline (22357.912 us; speedup 1.0000x reference)
//
#include <hip/hip_runtime.h>

#define NTRIAL 8
#define NNEUR 100
#define NTT 256
#define NT_FULL 300
#define NTAU 50
#define NLAT 8
#define NPAD 44
#define LRATE 0.2f
#define JITTER 0.001f
#define NMAT 64            // NTRIAL*NLAT batched 256x256 matrices

// ---------------- init ----------------
__global__ void k_zero(float* mu, float* scal){
    int i = blockIdx.x*256 + threadIdx.x;
    if (i < 16384) mu[i] = 0.f;
    if (i < 64) scal[i] = 0.f;
}

// kernel (i,tau,j) -> kt (i,j,tau) for coalesced conv staging
__global__ void k_transpose(const float* __restrict__ kern, float* __restrict__ kt){
    int idx = blockIdx.x*256 + threadIdx.x;
    if (idx >= NNEUR*NTAU*NNEUR) return;
    int i = idx/(NTAU*NNEUR); int rem = idx%(NTAU*NNEUR);
    int tau = rem/NNEUR; int j = rem%NNEUR;
    kt[((size_t)i*NNEUR + j)*NTAU + tau] = kern[idx];
}

// ---------------- conv + readout contraction ----------------
// W[(m*100+j)*8+l][t] = sum_i readout[i][l] * thresh( sum_{tau=1..50} kernel[i][tau-1][j]*raw[m][i][t+44-tau] )
__global__ __launch_bounds__(256) void k_conv_weights(const float* __restrict__ raw,
                                                      const float* __restrict__ kt,
                                                      const float* __restrict__ readout,
                                                      float* __restrict__ W){
    int b = blockIdx.x; int m = b / NNEUR; int j = b % NNEUR; int t = threadIdx.x;
    __shared__ float ro[NNEUR*NLAT];
    __shared__ float raw_s[10][NT_FULL];
    __shared__ float kern_s[10][NTAU];
    for (int idx = t; idx < NNEUR*NLAT; idx += 256) ro[idx] = readout[idx];
    float acc[NLAT];
    #pragma unroll
    for (int l = 0; l < NLAT; ++l) acc[l] = 0.f;
    int tmax = min(NTAU, t + NPAD);
    for (int c = 0; c < 10; ++c){
        __syncthreads();
        for (int idx = t; idx < 10*NT_FULL; idx += 256){
            int ii = idx / NT_FULL, tt = idx % NT_FULL;
            raw_s[ii][tt] = raw[((size_t)m*NNEUR + c*10 + ii)*NT_FULL + tt];
        }
        for (int idx = t; idx < 10*NTAU; idx += 256){
            int ii = idx / NTAU, tau = idx % NTAU;
            kern_s[ii][tau] = kt[((size_t)(c*10 + ii)*NNEUR + j)*NTAU + tau];
        }
        __syncthreads();
        for (int ii = 0; ii < 10; ++ii){
            float g = 0.f;
            const float* kr = kern_s[ii];
            const float* rr = raw_s[ii];
            for (int tau = 1; tau <= tmax; ++tau) g += kr[tau-1] * rr[t + NPAD - tau];
            if (fabsf(g) < 1e-5f) g = 0.f;   // ZERO_THRESH, applied before readout contraction
            const float* rop = &ro[(c*10 + ii)*NLAT];
            #pragma unroll
            for (int l = 0; l < NLAT; ++l) acc[l] += rop[l]*g;
        }
    }
    #pragma unroll
    for (int l = 0; l < NLAT; ++l) W[(((size_t)b)*NLAT + l)*NTT + t] = acc[l];
}

// ---------------- K' = K + jitter*I ----------------
__global__ void k_build_Kp(const float* __restrict__ K, float* __restrict__ A){
    int idx = blockIdx.x*256 + threadIdx.x;  // 65536
    int r = idx >> 8, c = idx & 255;
    float v = K[idx];
    if (r == c) v += JITTER;
    A[idx] = v;
}

// ---------------- batched in-place Cholesky (lower), + logdet ----------------
__global__ __launch_bounds__(256) void k_chol(float* __restrict__ Abase, float* __restrict__ logdet){
    float* M = Abase + (size_t)blockIdx.x * 65536;
    __shared__ float col[256];
    __shared__ float s_inv;
    __shared__ float red[256];
    int t = threadIdx.x;
    for (int k = 0; k < 256; ++k){
        if (t == 0){ float d = sqrtf(M[k*257]); M[k*257] = d; s_inv = 1.f/d; }
        __syncthreads();
        int r = k + 1 + t;
        float v = 0.f;
        if (r < 256){ v = M[(size_t)r*256 + k] * s_inv; M[(size_t)r*256 + k] = v; }
        col[t] = v;
        __syncthreads();
        if (r < 256){
            float* Mr = M + (size_t)r*256;
            for (int c = k + 1; c <= r; ++c) Mr[c] -= v * col[c - k - 1];
        }
        __syncthreads();
    }
    red[t] = 2.f * logf(M[t*257]);
    __syncthreads();
    for (int s = 128; s > 0; s >>= 1){ if (t < s) red[t] += red[t+s]; __syncthreads(); }
    if (t == 0) logdet[blockIdx.x] = red[0];
}

// ---------------- batched triangular inverse X = L^-1 (+ diag(A^-1)) ----------------
__global__ __launch_bounds__(256) void k_trinv(const float* __restrict__ Abase,
                                               float* __restrict__ Xbase,
                                               float* __restrict__ diagAinv){
    int b = blockIdx.x; int j = threadIdx.x;
    const float* L = Abase + (size_t)b * 65536;
    float* Xm = Xbase + (size_t)b * 65536;
    __shared__ float idiag[256];
    idiag[j] = 1.f / L[j*257];
    __syncthreads();
    float invd = idiag[j];
    Xm[(size_t)j*257] = invd;
    float dsum = invd*invd;
    for (int r = j + 1; r < 256; ++r){
        const float* Lr = L + (size_t)r*256;
        float s0=0.f, s1=0.f, s2=0.f, s3=0.f;
        int c = j;
        for (; c + 3 < r; c += 4){
            s0 += Lr[c]   * Xm[(size_t)c*256 + j];
            s1 += Lr[c+1] * Xm[(size_t)(c+1)*256 + j];
            s2 += Lr[c+2] * Xm[(size_t)(c+2)*256 + j];
            s3 += Lr[c+3] * Xm[(size_t)(c+3)*256 + j];
        }
        for (; c < r; ++c) s0 += Lr[c] * Xm[(size_t)c*256 + j];
        float v = -((s0+s1)+(s2+s3)) * idiag[r];
        Xm[(size_t)r*256 + j] = v;
        dsum += v*v;
    }
    if (diagAinv) diagAinv[b*256 + j] = dsum;
}

// ---------------- invK = X^T X (one-time) ----------------
__global__ __launch_bounds__(256) void k_syrk_invK(const float* __restrict__ X, float* __restrict__ invK){
    int i = blockIdx.x, j = threadIdx.x;
    int lo = max(i, j);
    float s = 0.f;
    for (int r = lo; r < 256; ++r) s += X[(size_t)r*256 + i] * X[(size_t)r*256 + j];
    invK[(size_t)i*256 + j] = s;
}

// ---------------- lambda (+ optional loss pieces) ----------------
__global__ __launch_bounds__(256) void k_lambda(const float* __restrict__ W, const float* __restrict__ mu,
                                                const float* __restrict__ diagAinv, const float* __restrict__ Y,
                                                const float* __restrict__ bias_p, float* __restrict__ lambd,
                                                int iter0, int do_loss, float* __restrict__ scal){
    int b = blockIdx.x; int m = b / NNEUR; int t = threadIdx.x;
    __shared__ float r1[256], r2[256];
    float bias = bias_p[0];
    float ll = bias, q = 0.f;
    #pragma unroll
    for (int l = 0; l < NLAT; ++l){
        float w   = W[(((size_t)b)*NLAT + l)*NTT + t];
        float muv = mu[((size_t)(m*NLAT + l))*NTT + t];
        float dh  = iter0 ? (1.0f + JITTER) : (-diagAinv[((size_t)(m*NLAT + l))*NTT + t]);
        ll += w * muv;
        q  += w * w * dh;
    }
    float lam = expf(ll + 0.5f*q);
    size_t idx = (size_t)b*NTT + t;
    lambd[idx] = lam;
    if (do_loss){
        r1[t] = Y[idx]*ll; r2[t] = lam;
        __syncthreads();
        for (int s = 128; s > 0; s >>= 1){ if (t < s){ r1[t]+=r1[t+s]; r2[t]+=r2[t+s]; } __syncthreads(); }
        if (t == 0){ atomicAdd(&scal[0], r1[0]); atomicAdd(&scal[1], r2[0]); }
    }
}

// ---------------- grad, w2l (+ optional muK.mu loss piece) ----------------
__global__ __launch_bounds__(256) void k_grad(const float* __restrict__ W, const float* __restrict__ Y,
                                              const float* __restrict__ lambd, const float* __restrict__ mu,
                                              const float* __restrict__ invK, float* __restrict__ grad,
                                              float* __restrict__ w2l, int do_loss, float* __restrict__ scal){
    int b = blockIdx.x; int m = b >> 3; int l = b & 7; int t = threadIdx.x;
    __shared__ float mus[256];
    __shared__ float red[256];
    mus[t] = mu[(size_t)b*NTT + t];
    __syncthreads();
    float mk = 0.f;
    for (int u = 0; u < 256; ++u) mk += mus[u] * invK[(size_t)u*256 + t];
    float g = 0.f, w2a = 0.f;
    for (int n = 0; n < NNEUR; ++n){
        size_t wi = (((size_t)(m*NNEUR + n))*NLAT + l)*NTT + t;
        size_t yi = ((size_t)(m*NNEUR + n))*NTT + t;
        float w = W[wi]; float lam = lambd[yi];
        g   += w * (Y[yi] - lam);
        w2a += w * w * lam;
    }
    grad[(size_t)b*NTT + t] = g - mk;
    w2l [(size_t)b*NTT + t] = w2a;
    if (do_loss){
        red[t] = mk * mus[t];
        __syncthreads();
        for (int s = 128; s > 0; s >>= 1){ if (t < s) red[t] += red[t+s]; __syncthreads(); }
        if (t == 0) atomicAdd(&scal[2], red[0]);
    }
}

// ---------------- A = invK + diag(w2l) (batched) ----------------
__global__ void k_build_A(const float* __restrict__ invK, const float* __restrict__ w2l, float* __restrict__ Abuf){
    size_t gid = (size_t)blockIdx.x*256 + threadIdx.x;   // 64*65536
    int b = (int)(gid >> 16); int e = (int)(gid & 65535); int r = e >> 8, c = e & 255;
    float v = invK[e];
    if (r == c) v += w2l[b*256 + r];
    Abuf[gid] = v;
}

// ---------------- mu += LR * X^T (X grad) ----------------
__global__ __launch_bounds__(256) void k_solve(const float* __restrict__ X, const float* __restrict__ grad,
                                               float* __restrict__ mu){
    int b = blockIdx.x, j = threadIdx.x;
    const float* Xm = X + (size_t)b * 65536;
    __shared__ float gs[256], ts[256];
    gs[j] = grad[(size_t)b*NTT + j];
    __syncthreads();
    float s = 0.f;
    const float* row = Xm + (size_t)j*256;
    for (int c = 0; c <= j; ++c) s += row[c] * gs[c];
    ts[j] = s;
    __syncthreads();
    float u = 0.f;
    for (int r = j; r < 256; ++r) u += Xm[(size_t)r*256 + j] * ts[r];
    mu[(size_t)b*NTT + j] += LRATE * u;
}

// ---------------- per-iteration loss scalars: trace(iKh), logabsdet(iKh) ----------------
__global__ __launch_bounds__(256) void k_iter_scalars(const float* __restrict__ w2l, const float* __restrict__ diagAinv,
                                                      const float* __restrict__ logdetA, const float* __restrict__ logdetKp,
                                                      float* __restrict__ slot_trace, float* __restrict__ slot_logabs){
    int b = blockIdx.x, t = threadIdx.x;
    __shared__ float red[256];
    red[t] = w2l[b*256 + t] * diagAinv[b*256 + t];
    __syncthreads();
    for (int s = 128; s > 0; s >>= 1){ if (t < s) red[t] += red[t+s]; __syncthreads(); }
    if (t == 0){
        atomicAdd(slot_trace,  -256.f + red[0]);                 // trace(invK * (-A^-1)) = -(256 - sum w2l*diagAinv)
        atomicAdd(slot_logabs, -logdetKp[0] - logdetA[b]);       // logdet(invK) - logdet(A)
    }
}

__global__ void k_loss(const float* __restrict__ scal, float* __restrict__ out_loss){
    // loss = sum(Y*ll) - sum(lam) - 0.5*muKmu - 0.5*trace + 0.5*logabs - nt
    out_loss[0] = scal[0] - scal[1] - 0.5f*scal[2] - 0.5f*scal[8+3] + 0.5f*scal[24+3] - 256.f;
}

__global__ void k_gather(const float* __restrict__ mu, const float* __restrict__ lambd, float* __restrict__ out){
    int idx = blockIdx.x*256 + threadIdx.x;
    if (idx < 16384) out[idx] = mu[idx];
    else if (idx < 16384 + 204800) out[idx] = lambd[idx - 16384];
}

extern "C" void kernel_launch(void* const* d_in, const int* in_sizes, int n_in,
                              void* d_out, int out_size, void* d_ws, size_t ws_size,
                              hipStream_t stream){
    (void)in_sizes; (void)n_in; (void)out_size; (void)ws_size;
    const float* Y       = (const float*)d_in[0];
    const float* raw     = (const float*)d_in[1];
    const float* kern    = (const float*)d_in[2];
    const float* readout = (const float*)d_in[3];
    const float* K       = (const float*)d_in[4];
    const float* bias    = (const float*)d_in[5];
    // d_in[6] = max_iter (device scalar, always 5 for this harness; unreadable during capture)
    float* out = (float*)d_out;
    float* ws  = (float*)d_ws;

    float* invK    = ws;                       // 65536
    float* Abuf    = invK + 65536;             // 64*65536
    float* Xbuf    = Abuf + (size_t)NMAT*65536;// 64*65536
    float* W       = Xbuf + (size_t)NMAT*65536;// 1,638,400
    float* mu      = W + 1638400;              // 16384
    float* lambd   = mu + 16384;               // 204800
    float* grad    = lambd + 204800;           // 16384
    float* w2l     = grad + 16384;             // 16384
    float* diag    = w2l + 16384;              // 16384
    float* logdetA = diag + 16384;             // 64
    float* scal    = logdetA + 64;             // 64  [0]=ylog [1]=lamsum [2]=muKmu [8+i]=trace_i [24+i]=logabs_i [20]=logdetKp
    float* kt      = scal + 64;                // 500,000
    // total ~43.5 MB

    k_zero<<<64, 256, 0, stream>>>(mu, scal);
    k_transpose<<<(NNEUR*NTAU*NNEUR + 255)/256, 256, 0, stream>>>(kern, kt);
    k_conv_weights<<<NTRIAL*NNEUR, 256, 0, stream>>>(raw, kt, readout, W);

    // one-time: invK = (K + jitter I)^-1 via Cholesky, plus logdet(K')
    k_build_Kp<<<256, 256, 0, stream>>>(K, Abuf);
    k_chol<<<1, 256, 0, stream>>>(Abuf, scal + 20);
    k_trinv<<<1, 256, 0, stream>>>(Abuf, Xbuf, nullptr);
    k_syrk_invK<<<256, 256, 0, stream>>>(Xbuf, invK);

    for (int it = 0; it < 5; ++it){
        int first = (it == 0) ? 1 : 0;
        int last  = (it == 4) ? 1 : 0;
        k_lambda<<<NTRIAL*NNEUR, 256, 0, stream>>>(W, mu, diag, Y, bias, lambd, first, last, scal);
        k_grad<<<NMAT, 256, 0, stream>>>(W, Y, lambd, mu, invK, grad, w2l, last, scal);
        k_build_A<<<NMAT*256, 256, 0, stream>>>(invK, w2l, Abuf);
        k_chol<<<NMAT, 256, 0, stream>>>(Abuf, logdetA);
        k_trinv<<<NMAT, 256, 0, stream>>>(Abuf, Xbuf, diag);
        k_solve<<<NMAT, 256, 0, stream>>>(Xbuf, grad, mu);
        k_iter_scalars<<<NMAT, 256, 0, stream>>>(w2l, diag, logdetA, scal + 20, scal + 8 + it, scal + 24 + it);
    }
    k_loss<<<1, 1, 0, stream>>>(scal, out + 16384 + 204800);
    k_gather<<<864, 256, 0, stream>>>(mu, lambd, out);
}

// Round 2
// 8412.600 us; speedup vs baseline: 2.6577x; 2.6577x over previous
//
#include <hip/hip_runtime.h>

#define NTRIAL 8
#define NNEUR 100
#define NTT 256
#define NT_FULL 300
#define NTAU 50
#define NLAT 8
#define NPAD 44
#define LRATE 0.2f
#define JITTER 0.001f
#define NMAT 64            // NTRIAL*NLAT batched 256x256 matrices
#define NPACK 32896        // 256*257/2 packed lower-triangle elements

// ---------------- init ----------------
__global__ void k_zero(float* mu, float* scal){
    int i = blockIdx.x*256 + threadIdx.x;
    if (i < 16384) mu[i] = 0.f;
    if (i < 64) scal[i] = 0.f;
}

// kernel (i,tau,j) -> kt (i,j,tau) for coalesced conv staging
__global__ void k_transpose(const float* __restrict__ kern, float* __restrict__ kt){
    int idx = blockIdx.x*256 + threadIdx.x;
    if (idx >= NNEUR*NTAU*NNEUR) return;
    int i = idx/(NTAU*NNEUR); int rem = idx%(NTAU*NNEUR);
    int tau = rem/NNEUR; int j = rem%NNEUR;
    kt[((size_t)i*NNEUR + j)*NTAU + tau] = kern[idx];
}

// ---------------- conv + readout contraction ----------------
__global__ __launch_bounds__(256) void k_conv_weights(const float* __restrict__ raw,
                                                      const float* __restrict__ kt,
                                                      const float* __restrict__ readout,
                                                      float* __restrict__ W){
    int b = blockIdx.x; int m = b / NNEUR; int j = b % NNEUR; int t = threadIdx.x;
    __shared__ float ro[NNEUR*NLAT];
    __shared__ float raw_s[10][NT_FULL];
    __shared__ float kern_s[10][NTAU];
    for (int idx = t; idx < NNEUR*NLAT; idx += 256) ro[idx] = readout[idx];
    float acc[NLAT];
    #pragma unroll
    for (int l = 0; l < NLAT; ++l) acc[l] = 0.f;
    int tmax = min(NTAU, t + NPAD);
    for (int c = 0; c < 10; ++c){
        __syncthreads();
        for (int idx = t; idx < 10*NT_FULL; idx += 256){
            int ii = idx / NT_FULL, tt = idx % NT_FULL;
            raw_s[ii][tt] = raw[((size_t)m*NNEUR + c*10 + ii)*NT_FULL + tt];
        }
        for (int idx = t; idx < 10*NTAU; idx += 256){
            int ii = idx / NTAU, tau = idx % NTAU;
            kern_s[ii][tau] = kt[((size_t)(c*10 + ii)*NNEUR + j)*NTAU + tau];
        }
        __syncthreads();
        for (int ii = 0; ii < 10; ++ii){
            float g = 0.f;
            const float* kr = kern_s[ii];
            const float* rr = raw_s[ii];
            for (int tau = 1; tau <= tmax; ++tau) g += kr[tau-1] * rr[t + NPAD - tau];
            if (fabsf(g) < 1e-5f) g = 0.f;   // ZERO_THRESH before readout contraction
            const float* rop = &ro[(c*10 + ii)*NLAT];
            #pragma unroll
            for (int l = 0; l < NLAT; ++l) acc[l] += rop[l]*g;
        }
    }
    #pragma unroll
    for (int l = 0; l < NLAT; ++l) W[(((size_t)b)*NLAT + l)*NTT + t] = acc[l];
}

// ---------------- fused LDS-resident Cholesky + in-place triangular inverse ----------------
// MODE 0: one block. Input Kin (full 256x256) + jitter. Output: Xp = packed L^-1 (diag = 1/L_rr),
//         logdetKp[0] = logdet(K').
// MODE 1: NMAT blocks. Input invKp (packed) + diag(w2l). Computes diag(A^-1), logdet(A),
//         mu += LR * X^T (X grad), and the trace/logabs loss atomics.
template<int MODE>
__global__ __launch_bounds__(256) void k_fact(const float* __restrict__ Kin,
                                              const float* __restrict__ invKp,
                                              const float* __restrict__ w2l,
                                              const float* __restrict__ grad,
                                              float* __restrict__ mu,
                                              float* __restrict__ diagAinv,
                                              float* __restrict__ Xp,
                                              float* __restrict__ logdetKp,
                                              float* __restrict__ slot_trace,
                                              float* __restrict__ slot_logabs){
    __shared__ float P[NPACK];    // packed lower triangle, row r at r(r+1)/2
    __shared__ float aux[257];
    __shared__ float idg[256];
    __shared__ float gs[256];
    const int t = threadIdx.x;
    const int b = blockIdx.x;

    // ---- load ----
    if (MODE == 0){
        for (int r = 0; r < 256; ++r)
            if (t <= r) P[((r*(r+1))>>1) + t] = Kin[r*256 + t] + ((t==r) ? JITTER : 0.f);
    } else {
        for (int e = t; e < NPACK; e += 256) P[e] = invKp[e];
        __syncthreads();
        P[((t*(t+1))>>1) + t] += w2l[b*256 + t];
    }
    __syncthreads();

    // ---- Cholesky (right-looking, rank-1). Diagonal kept as L_kk^2 (never overwritten). ----
    for (int k = 0; k < 255; ++k){
        float sinv = 1.f / sqrtf(P[((k*(k+1))>>1) + k]);
        int r = k + 1 + t;
        float v = 0.f; int roff = 0;
        if (r < 256){
            roff = (r*(r+1))>>1;
            v = P[roff + k] * sinv;
            P[roff + k] = v;
        }
        aux[t] = v;                      // aux[i] = L[k+1+i][k]
        __syncthreads();
        if (r < 256){
            float* Pr = &P[roff];
            #pragma unroll 4
            for (int c = k+1; c <= r; ++c) Pr[c] -= v * aux[c - k - 1];
        }
        __syncthreads();
    }

    // ---- logdet + inverse diag ----
    {
        float d = P[((t*(t+1))>>1) + t];   // = L_tt^2
        idg[t] = 1.f / sqrtf(d);
        aux[t] = logf(d);                  // sum gives 2*sum(log L_tt)
    }
    __syncthreads();
    for (int s = 128; s > 0; s >>= 1){ if (t < s) aux[t] += aux[t+s]; __syncthreads(); }
    const float logdetA = aux[0];
    if (MODE == 0 && t == 0) logdetKp[0] = logdetA;

    // ---- in-place triangular inverse: row-serial wavefront. Rows < r already hold X. ----
    for (int r = 1; r < 256; ++r){
        const int roff = (r*(r+1))>>1;
        float s = 0.f;
        if (t < r){
            const float* Pr = &P[roff];          // row r: still original L
            s = Pr[t] * idg[t];                  // c = t term (X[t][t] = idg[t])
            int offc = ((t+1)*(t+2))>>1;
            #pragma unroll 4
            for (int c = t+1; c < r; ++c){ s += Pr[c] * P[offc + t]; offc += c + 1; }
        }
        __syncthreads();                         // all reads of row r done
        if (t < r) P[roff + t] = -s * idg[r];    // row r becomes X
        __syncthreads();
    }

    if (MODE == 0){
        // store packed X with diag = 1/L_rr
        P[((t*(t+1))>>1) + t] = idg[t];
        __syncthreads();
        for (int e = t; e < NPACK; e += 256) Xp[e] = P[e];
        return;
    } else {
        // ---- diag(A^-1)_t = sum_r X[r][t]^2 ----
        float dsum = idg[t]*idg[t];
        {
            int offr = ((t+1)*(t+2))>>1;
            for (int r = t+1; r < 256; ++r){ float x = P[offr + t]; dsum += x*x; offr += r + 1; }
        }
        diagAinv[b*256 + t] = dsum;

        // ---- mu += LR * X^T (X g) ----
        gs[t] = grad[b*256 + t];
        __syncthreads();
        float tr = idg[t] * gs[t];
        {
            const float* Pr = &P[(t*(t+1))>>1];
            for (int c = 0; c < t; ++c) tr += Pr[c] * gs[c];
        }
        __syncthreads();
        aux[t] = tr;
        __syncthreads();
        float u = idg[t] * aux[t];
        {
            int offr = ((t+1)*(t+2))>>1;
            for (int r = t+1; r < 256; ++r){ u += P[offr + t] * aux[r]; offr += r + 1; }
        }
        mu[b*256 + t] += LRATE * u;

        // ---- loss scalars ----
        gs[t] = w2l[b*256 + t] * dsum;
        __syncthreads();
        for (int s = 128; s > 0; s >>= 1){ if (t < s) gs[t] += gs[t+s]; __syncthreads(); }
        if (t == 0){
            atomicAdd(slot_trace,  gs[0] - 256.f);               // trace(invK * -A^-1)
            atomicAdd(slot_logabs, -logdetKp[0] - logdetA);      // logdet(invK) - logdet(A)
        }
    }
}

// ---------------- invK = X^T X from packed X (full + packed outputs) ----------------
__global__ __launch_bounds__(256) void k_syrk(const float* __restrict__ Xp,
                                              float* __restrict__ invK,
                                              float* __restrict__ invKp){
    int i = blockIdx.x, j = threadIdx.x;
    int lo = max(i, j);
    float s = 0.f;
    int offr = (lo*(lo+1))>>1;
    for (int r = lo; r < 256; ++r){ s += Xp[offr + i] * Xp[offr + j]; offr += r + 1; }
    invK[(size_t)i*256 + j] = s;
    if (j <= i) invKp[((i*(i+1))>>1) + j] = s;
}

// ---------------- lambda (+ optional loss pieces) ----------------
__global__ __launch_bounds__(256) void k_lambda(const float* __restrict__ W, const float* __restrict__ mu,
                                                const float* __restrict__ diagAinv, const float* __restrict__ Y,
                                                const float* __restrict__ bias_p, float* __restrict__ lambd,
                                                int iter0, int do_loss, float* __restrict__ scal){
    int b = blockIdx.x; int m = b / NNEUR; int t = threadIdx.x;
    __shared__ float r1[256], r2[256];
    float bias = bias_p[0];
    float ll = bias, q = 0.f;
    #pragma unroll
    for (int l = 0; l < NLAT; ++l){
        float w   = W[(((size_t)b)*NLAT + l)*NTT + t];
        float muv = mu[((size_t)(m*NLAT + l))*NTT + t];
        float dh  = iter0 ? (1.0f + JITTER) : (-diagAinv[((size_t)(m*NLAT + l))*NTT + t]);
        ll += w * muv;
        q  += w * w * dh;
    }
    float lam = expf(ll + 0.5f*q);
    size_t idx = (size_t)b*NTT + t;
    lambd[idx] = lam;
    if (do_loss){
        r1[t] = Y[idx]*ll; r2[t] = lam;
        __syncthreads();
        for (int s = 128; s > 0; s >>= 1){ if (t < s){ r1[t]+=r1[t+s]; r2[t]+=r2[t+s]; } __syncthreads(); }
        if (t == 0){ atomicAdd(&scal[0], r1[0]); atomicAdd(&scal[1], r2[0]); }
    }
}

// ---------------- grad, w2l (+ optional muK.mu loss piece) ----------------
__global__ __launch_bounds__(256) void k_grad(const float* __restrict__ W, const float* __restrict__ Y,
                                              const float* __restrict__ lambd, const float* __restrict__ mu,
                                              const float* __restrict__ invK, float* __restrict__ grad,
                                              float* __restrict__ w2l, int do_loss, float* __restrict__ scal){
    int b = blockIdx.x; int m = b >> 3; int l = b & 7; int t = threadIdx.x;
    __shared__ float mus[256];
    __shared__ float red[256];
    mus[t] = mu[(size_t)b*NTT + t];
    __syncthreads();
    float mk = 0.f;
    for (int u = 0; u < 256; ++u) mk += mus[u] * invK[(size_t)u*256 + t];
    float g = 0.f, w2a = 0.f;
    for (int n = 0; n < NNEUR; ++n){
        size_t wi = (((size_t)(m*NNEUR + n))*NLAT + l)*NTT + t;
        size_t yi = ((size_t)(m*NNEUR + n))*NTT + t;
        float w = W[wi]; float lam = lambd[yi];
        g   += w * (Y[yi] - lam);
        w2a += w * w * lam;
    }
    grad[(size_t)b*NTT + t] = g - mk;
    w2l [(size_t)b*NTT + t] = w2a;
    if (do_loss){
        red[t] = mk * mus[t];
        __syncthreads();
        for (int s = 128; s > 0; s >>= 1){ if (t < s) red[t] += red[t+s]; __syncthreads(); }
        if (t == 0) atomicAdd(&scal[2], red[0]);
    }
}

__global__ void k_loss(const float* __restrict__ scal, float* __restrict__ out_loss){
    // loss = sum(Y*ll) - sum(lam) - 0.5*muKmu - 0.5*trace + 0.5*logabs - nt
    out_loss[0] = scal[0] - scal[1] - 0.5f*scal[2] - 0.5f*scal[8+3] + 0.5f*scal[24+3] - 256.f;
}

__global__ void k_gather(const float* __restrict__ mu, const float* __restrict__ lambd, float* __restrict__ out){
    int idx = blockIdx.x*256 + threadIdx.x;
    if (idx < 16384) out[idx] = mu[idx];
    else if (idx < 16384 + 204800) out[idx] = lambd[idx - 16384];
}

extern "C" void kernel_launch(void* const* d_in, const int* in_sizes, int n_in,
                              void* d_out, int out_size, void* d_ws, size_t ws_size,
                              hipStream_t stream){
    (void)in_sizes; (void)n_in; (void)out_size; (void)ws_size;
    const float* Y       = (const float*)d_in[0];
    const float* raw     = (const float*)d_in[1];
    const float* kern    = (const float*)d_in[2];
    const float* readout = (const float*)d_in[3];
    const float* K       = (const float*)d_in[4];
    const float* bias    = (const float*)d_in[5];
    float* out = (float*)d_out;
    float* ws  = (float*)d_ws;

    float* invK    = ws;                       // 65536
    float* invKp   = invK + 65536;             // 32896 packed
    float* Xp      = invKp + 32896;            // 32896 packed
    float* W       = Xp + 32896;               // 1,638,400
    float* mu      = W + 1638400;              // 16384
    float* lambd   = mu + 16384;               // 204800
    float* grad    = lambd + 204800;           // 16384
    float* w2l     = grad + 16384;             // 16384
    float* diag    = w2l + 16384;              // 16384
    float* scal    = diag + 16384;             // 64: [0]=ylog [1]=lamsum [2]=muKmu [8+i]=trace_i [20]=logdetKp [24+i]=logabs_i
    float* kt      = scal + 64;                // 500,000
    // total ~10 MB

    k_zero<<<64, 256, 0, stream>>>(mu, scal);
    k_transpose<<<(NNEUR*NTAU*NNEUR + 255)/256, 256, 0, stream>>>(kern, kt);
    k_conv_weights<<<NTRIAL*NNEUR, 256, 0, stream>>>(raw, kt, readout, W);

    // one-time: X = chol(K')^-1 (packed), logdet(K'); then invK = X^T X
    k_fact<0><<<1, 256, 0, stream>>>(K, nullptr, nullptr, nullptr, nullptr, nullptr,
                                     Xp, scal + 20, nullptr, nullptr);
    k_syrk<<<256, 256, 0, stream>>>(Xp, invK, invKp);

    for (int it = 0; it < 5; ++it){
        int first = (it == 0) ? 1 : 0;
        int last  = (it == 4) ? 1 : 0;
        k_lambda<<<NTRIAL*NNEUR, 256, 0, stream>>>(W, mu, diag, Y, bias, lambd, first, last, scal);
        k_grad<<<NMAT, 256, 0, stream>>>(W, Y, lambd, mu, invK, grad, w2l, last, scal);
        k_fact<1><<<NMAT, 256, 0, stream>>>(nullptr, invKp, w2l, grad, mu, diag,
                                            nullptr, scal + 20, scal + 8 + it, scal + 24 + it);
    }
    k_loss<<<1, 1, 0, stream>>>(scal, out + 16384 + 204800);
    k_gather<<<864, 256, 0, stream>>>(mu, lambd, out);
}

// Round 3
// 2001.595 us; speedup vs baseline: 11.1700x; 4.2029x over previous
//
#include <hip/hip_runtime.h>

#define NTRIAL 8
#define NNEUR 100
#define NTT 256
#define NT_FULL 300
#define NTAU 50
#define NLAT 8
#define NPAD 44
#define LRATE 0.2f
#define JITTER 0.001f
#define NMAT 64            // NTRIAL*NLAT batched 256x256 matrices
#define NSLOT 136          // 16*17/2 lower 16x16 blocks
#define SPITCH 260         // floats per block slot (256 + 4 pad; rotates banks by 4)
#define NBLKF 35360        // NSLOT*SPITCH floats in a blocked matrix
#define NBLKF4 8840        // float4 count

// blocked-triangular layout helpers (shared by LDS and global blocked arrays)
__device__ __forceinline__ int bslot(int I, int J){ return ((I*(I+1))>>1) + J; }
// element (row i, col j) within block slot (I,J); chunk-XOR swizzle for bank spread
__device__ __forceinline__ int eidx(int I, int J, int i, int j){
    return bslot(I,J)*SPITCH + i*16 + ((((j>>2) + (i>>2))&3)<<2) + (j&3);
}
// float4 index of logical chunk q (cols 4q..4q+3) of row i
__device__ __forceinline__ int f4idx(int I, int J, int i, int q){
    return bslot(I,J)*65 + i*4 + ((q + (i>>2))&3);
}

// ---------------- init ----------------
__global__ void k_zero(float* mu, float* scal){
    int i = blockIdx.x*256 + threadIdx.x;
    if (i < 16384) mu[i] = 0.f;
    if (i < 64) scal[i] = 0.f;
}

// kernel (i,tau,j) -> kt (i,j,tau) for coalesced conv staging
__global__ void k_transpose(const float* __restrict__ kern, float* __restrict__ kt){
    int idx = blockIdx.x*256 + threadIdx.x;
    if (idx >= NNEUR*NTAU*NNEUR) return;
    int i = idx/(NTAU*NNEUR); int rem = idx%(NTAU*NNEUR);
    int tau = rem/NNEUR; int j = rem%NNEUR;
    kt[((size_t)i*NNEUR + j)*NTAU + tau] = kern[idx];
}

// ---------------- conv + readout contraction ----------------
__global__ __launch_bounds__(256) void k_conv_weights(const float* __restrict__ raw,
                                                      const float* __restrict__ kt,
                                                      const float* __restrict__ readout,
                                                      float* __restrict__ W){
    int b = blockIdx.x; int m = b / NNEUR; int j = b % NNEUR; int t = threadIdx.x;
    __shared__ float ro[NNEUR*NLAT];
    __shared__ float raw_s[10][NT_FULL];
    __shared__ float kern_s[10][NTAU];
    for (int idx = t; idx < NNEUR*NLAT; idx += 256) ro[idx] = readout[idx];
    float acc[NLAT];
    #pragma unroll
    for (int l = 0; l < NLAT; ++l) acc[l] = 0.f;
    int tmax = min(NTAU, t + NPAD);
    for (int c = 0; c < 10; ++c){
        __syncthreads();
        for (int idx = t; idx < 10*NT_FULL; idx += 256){
            int ii = idx / NT_FULL, tt = idx % NT_FULL;
            raw_s[ii][tt] = raw[((size_t)m*NNEUR + c*10 + ii)*NT_FULL + tt];
        }
        for (int idx = t; idx < 10*NTAU; idx += 256){
            int ii = idx / NTAU, tau = idx % NTAU;
            kern_s[ii][tau] = kt[((size_t)(c*10 + ii)*NNEUR + j)*NTAU + tau];
        }
        __syncthreads();
        for (int ii = 0; ii < 10; ++ii){
            float g = 0.f;
            const float* kr = kern_s[ii];
            const float* rr = raw_s[ii];
            for (int tau = 1; tau <= tmax; ++tau) g += kr[tau-1] * rr[t + NPAD - tau];
            if (fabsf(g) < 1e-5f) g = 0.f;   // ZERO_THRESH before readout contraction
            const float* rop = &ro[(c*10 + ii)*NLAT];
            #pragma unroll
            for (int l = 0; l < NLAT; ++l) acc[l] += rop[l]*g;
        }
    }
    #pragma unroll
    for (int l = 0; l < NLAT; ++l) W[(((size_t)b)*NLAT + l)*NTT + t] = acc[l];
}

// ============ fused blocked LDS Cholesky + in-place blocked triangular inverse ============
// MODE 0: 1 block. In: Kin (full row-major) + jitter. Out: Sblk = X^T blocked (X = L^-1),
//         logdetKp[0] = logdet(K').
// MODE 1: NMAT blocks. In: invKb (blocked) + diag(w2l). Out: diagAinv, mu += LR*A^-1 grad,
//         trace/logabs loss atomics.
template<int MODE>
__global__ __launch_bounds__(256) void k_fact(const float* __restrict__ Kin,
                                              const float* __restrict__ invKb,
                                              const float* __restrict__ w2l,
                                              const float* __restrict__ grad,
                                              float* __restrict__ mu,
                                              float* __restrict__ diagAinv,
                                              float* __restrict__ Sout,
                                              float* __restrict__ logdetKp,
                                              float* __restrict__ slot_trace,
                                              float* __restrict__ slot_logabs){
    __shared__ float4 P4[NBLKF4];      // 141,440 B : blocked lower-tri matrix
    __shared__ float4 Bs4[1040];       //  16,640 B : 16 groups x 16x16 B-scratch (overlaid later)
    __shared__ float dlog[256];        // chol diag values
    __shared__ float idg[16];          // 1/L_cc of current panel
    float* P  = (float*)P4;
    float* Bs = (float*)Bs4;
    const int t = threadIdx.x;
    const int b = blockIdx.x;

    // ---------------- load ----------------
    if (MODE == 0){
        int r = t, I = r>>4, i = r&15;
        for (int c = 0; c <= r; ++c)
            P[eidx(I, c>>4, i, c&15)] = Kin[r*256 + c] + ((c==r) ? JITTER : 0.f);
    } else {
        const float4* G4 = (const float4*)invKb;
        for (int e = t; e < NBLKF4; e += 256) P4[e] = G4[e];
        __syncthreads();
        int r = t, I = r>>4, i = r&15;
        P[eidx(I,I,i,i)] += w2l[b*256 + r];
    }

    const int g  = t >> 4;            // 16 groups of 16
    const int gt = t & 15;
    const int ti = (gt>>2)<<2;        // 4x4 tile coords
    const int tj = (gt&3)<<2;

    // ---------------- blocked Cholesky ----------------
    for (int p = 0; p < 16; ++p){
        __syncthreads();
        // (a) micro-chol of blk(p,p): lanes 0..15 of wave 0, lockstep, no barriers
        if (t < 16){
            const int i = t;
            float x[16];
            #pragma unroll
            for (int q = 0; q < 4; ++q){
                float4 v = P4[f4idx(p,p,i,q)];
                x[4*q+0]=v.x; x[4*q+1]=v.y; x[4*q+2]=v.z; x[4*q+3]=v.w;
            }
            #pragma unroll
            for (int k = 0; k < 16; ++k){
                float piv = __shfl(x[k], k, 64);
                float d = sqrtf(piv);
                float dinv = 1.f/d;
                float lik = (i == k) ? d : x[k]*dinv;
                if (i >= k) x[k] = lik;
                #pragma unroll
                for (int c = k+1; c < 16; ++c){
                    float lck = __shfl(x[k], c, 64);
                    if (i >= c) x[c] -= lik*lck;
                }
                if (i == k){ idg[k] = dinv; dlog[p*16+k] = d; }
            }
            #pragma unroll
            for (int q = 0; q < 4; ++q)
                P4[f4idx(p,p,i,q)] = make_float4(x[4*q],x[4*q+1],x[4*q+2],x[4*q+3]);
        }
        __syncthreads();
        if (p == 15) break;
        // (b) panel solve: L_Ip = A_Ip * L_pp^-T, one row per thread
        int nrows = (15 - p)*16;
        if (t < nrows){
            int r = (p+1)*16 + t;
            int I = r>>4, i = r&15;
            float x[16];
            #pragma unroll
            for (int q = 0; q < 4; ++q){
                float4 v = P4[f4idx(I,p,i,q)];
                x[4*q+0]=v.x; x[4*q+1]=v.y; x[4*q+2]=v.z; x[4*q+3]=v.w;
            }
            #pragma unroll
            for (int c = 0; c < 16; ++c){
                float s = x[c];
                #pragma unroll
                for (int j = 0; j < c; ++j) s -= x[j]*P[eidx(p,p,c,j)];
                x[c] = s*idg[c];
            }
            #pragma unroll
            for (int q = 0; q < 4; ++q)
                P4[f4idx(I,p,i,q)] = make_float4(x[4*q],x[4*q+1],x[4*q+2],x[4*q+3]);
        }
        __syncthreads();
        // (c) trailing update: A_IJ -= L_Ip * L_Jp^T (register 4x4 tiles, float4 row loads)
        int m = 15 - p;
        int npairs = (m*(m+1))>>1;
        for (int q = g; q < npairs; q += 16){
            int di = (int)floorf((sqrtf(8.f*(float)q + 1.f) - 1.f)*0.5f);
            while (((di+1)*(di+2))>>1 <= q) ++di;
            while ((di*(di+1))>>1 > q) --di;
            int dj = q - ((di*(di+1))>>1);
            int I = p+1+di, J = p+1+dj;
            float acc[4][4];
            #pragma unroll
            for (int aa=0;aa<4;++aa){ acc[aa][0]=0;acc[aa][1]=0;acc[aa][2]=0;acc[aa][3]=0; }
            #pragma unroll
            for (int kc = 0; kc < 4; ++kc){
                float4 a0 = P4[f4idx(I,p,ti+0,kc)];
                float4 a1 = P4[f4idx(I,p,ti+1,kc)];
                float4 a2 = P4[f4idx(I,p,ti+2,kc)];
                float4 a3 = P4[f4idx(I,p,ti+3,kc)];
                float4 b0 = P4[f4idx(J,p,tj+0,kc)];
                float4 b1 = P4[f4idx(J,p,tj+1,kc)];
                float4 b2 = P4[f4idx(J,p,tj+2,kc)];
                float4 b3 = P4[f4idx(J,p,tj+3,kc)];
                #define DOT4(u,v) (u.x*v.x + u.y*v.y + u.z*v.z + u.w*v.w)
                acc[0][0]+=DOT4(a0,b0); acc[0][1]+=DOT4(a0,b1); acc[0][2]+=DOT4(a0,b2); acc[0][3]+=DOT4(a0,b3);
                acc[1][0]+=DOT4(a1,b0); acc[1][1]+=DOT4(a1,b1); acc[1][2]+=DOT4(a1,b2); acc[1][3]+=DOT4(a1,b3);
                acc[2][0]+=DOT4(a2,b0); acc[2][1]+=DOT4(a2,b1); acc[2][2]+=DOT4(a2,b2); acc[2][3]+=DOT4(a2,b3);
                acc[3][0]+=DOT4(a3,b0); acc[3][1]+=DOT4(a3,b1); acc[3][2]+=DOT4(a3,b2); acc[3][3]+=DOT4(a3,b3);
            }
            #pragma unroll
            for (int aa = 0; aa < 4; ++aa){
                int oi = f4idx(I,J,ti+aa,tj>>2);
                float4 c = P4[oi];
                c.x -= acc[aa][0]; c.y -= acc[aa][1]; c.z -= acc[aa][2]; c.w -= acc[aa][3];
                P4[oi] = c;
            }
        }
    }

    // ---------------- blocked in-place triangular inverse, stored transposed ----------------
    // After: slot(I,J) holds S_IJ[a][b] = X[16I+b][16J+a]  (X = L^-1); diag slots upper-tri w/ zeros.
    for (int I = 0; I < 16; ++I){
        // phase 1: micro-invert S_II (wave0) concurrent with B_IJ = sum_K L_IK X_KJ (groups J<I)
        if (t < 16){
            const int j = t;           // column j of X_II == row j of S_II
            float col[16];
            #pragma unroll
            for (int k=0;k<16;++k) col[k] = 0.f;
            #pragma unroll
            for (int i = 0; i < 16; ++i){
                float Lii = P[eidx(I,I,i,i)];
                float s = 0.f;
                #pragma unroll
                for (int k = 0; k < 16; ++k){
                    if (k < i){ float term = P[eidx(I,I,i,k)]*col[k]; s += (k >= j) ? term : 0.f; }
                }
                col[i] = (i == j) ? (1.f/Lii) : ((i > j) ? (-s/Lii) : 0.f);
            }
            #pragma unroll
            for (int q = 0; q < 4; ++q)
                P4[f4idx(I,I,j,q)] = make_float4(col[4*q],col[4*q+1],col[4*q+2],col[4*q+3]);
        }
        if (g < I){
            const int J = g;
            float acc[4][4];
            #pragma unroll
            for (int aa=0;aa<4;++aa){ acc[aa][0]=0;acc[aa][1]=0;acc[aa][2]=0;acc[aa][3]=0; }
            for (int K = J; K < I; ++K){
                #pragma unroll
                for (int kc = 0; kc < 4; ++kc){
                    float4 a0 = P4[f4idx(I,K,ti+0,kc)];
                    float4 a1 = P4[f4idx(I,K,ti+1,kc)];
                    float4 a2 = P4[f4idx(I,K,ti+2,kc)];
                    float4 a3 = P4[f4idx(I,K,ti+3,kc)];
                    float4 b0 = P4[f4idx(K,J,tj+0,kc)];
                    float4 b1 = P4[f4idx(K,J,tj+1,kc)];
                    float4 b2 = P4[f4idx(K,J,tj+2,kc)];
                    float4 b3 = P4[f4idx(K,J,tj+3,kc)];
                    acc[0][0]+=DOT4(a0,b0); acc[0][1]+=DOT4(a0,b1); acc[0][2]+=DOT4(a0,b2); acc[0][3]+=DOT4(a0,b3);
                    acc[1][0]+=DOT4(a1,b0); acc[1][1]+=DOT4(a1,b1); acc[1][2]+=DOT4(a1,b2); acc[1][3]+=DOT4(a1,b3);
                    acc[2][0]+=DOT4(a2,b0); acc[2][1]+=DOT4(a2,b1); acc[2][2]+=DOT4(a2,b2); acc[2][3]+=DOT4(a2,b3);
                    acc[3][0]+=DOT4(a3,b0); acc[3][1]+=DOT4(a3,b1); acc[3][2]+=DOT4(a3,b2); acc[3][3]+=DOT4(a3,b3);
                }
            }
            #pragma unroll
            for (int aa = 0; aa < 4; ++aa)
                Bs4[g*65 + (ti+aa)*4 + (((tj>>2) + ((ti+aa)>>2))&3)] =
                    make_float4(acc[aa][0],acc[aa][1],acc[aa][2],acc[aa][3]);
        }
        __syncthreads();
        // phase 2: S_IJ[b][a] = - sum_k S_II[k][a] * B[k][b]
        if (g < I){
            const int J = g;
            float acc2[4][4];
            #pragma unroll
            for (int aa=0;aa<4;++aa){ acc2[aa][0]=0;acc2[aa][1]=0;acc2[aa][2]=0;acc2[aa][3]=0; }
            #pragma unroll
            for (int k = 0; k < 16; ++k){
                float4 sa = P4[f4idx(I,I,k,ti>>2)];                       // S_II[k][ti..ti+3]
                float4 bb = Bs4[g*65 + k*4 + (((tj>>2) + (k>>2))&3)];      // B[k][tj..tj+3]
                acc2[0][0]+=sa.x*bb.x; acc2[0][1]+=sa.x*bb.y; acc2[0][2]+=sa.x*bb.z; acc2[0][3]+=sa.x*bb.w;
                acc2[1][0]+=sa.y*bb.x; acc2[1][1]+=sa.y*bb.y; acc2[1][2]+=sa.y*bb.z; acc2[1][3]+=sa.y*bb.w;
                acc2[2][0]+=sa.z*bb.x; acc2[2][1]+=sa.z*bb.y; acc2[2][2]+=sa.z*bb.z; acc2[2][3]+=sa.z*bb.w;
                acc2[3][0]+=sa.w*bb.x; acc2[3][1]+=sa.w*bb.y; acc2[3][2]+=sa.w*bb.z; acc2[3][3]+=sa.w*bb.w;
            }
            // acc2[aa][bb] = sum_k S_II[k][ti+aa]*B[k][tj+bb]; write S_IJ row (tj+bb), chunk ti>>2
            #pragma unroll
            for (int bb = 0; bb < 4; ++bb)
                P4[f4idx(I,J,tj+bb,ti>>2)] =
                    make_float4(-acc2[0][bb],-acc2[1][bb],-acc2[2][bb],-acc2[3][bb]);
        }
        __syncthreads();
    }

    // ---------------- epilogue ----------------
    float* gsp = Bs;          // overlays (Bs dead after trinv)
    float* zp  = Bs + 256;
    float* rdp = Bs + 512;

    if (MODE == 0){
        rdp[t] = 2.f*logf(dlog[t]);
        __syncthreads();
        for (int s = 128; s > 0; s >>= 1){ if (t < s) rdp[t] += rdp[t+s]; __syncthreads(); }
        if (t == 0) logdetKp[0] = rdp[0];
        float4* SO = (float4*)Sout;
        for (int e = t; e < NBLKF4; e += 256) SO[e] = P4[e];
        return;
    } else {
        const int J0 = t>>4, j0 = t&15;
        // diag(A^-1)_t = sum over I>=J0 of |S_IJ0 row j0|^2
        float dsum = 0.f;
        for (int I = J0; I < 16; ++I){
            #pragma unroll
            for (int q = 0; q < 4; ++q){
                float4 v = P4[f4idx(I,J0,j0,q)];
                dsum += v.x*v.x + v.y*v.y + v.z*v.z + v.w*v.w;
            }
        }
        diagAinv[b*256 + t] = dsum;
        float w2v = w2l[b*256 + t];
        gsp[t] = grad[b*256 + t];
        __syncthreads();
        // z_r = (X g)_r = sum_{J<=I} sum_j S_IJ[j][rb] * g[16J+j]
        {
            const int Ir = t>>4, rb = t&15;
            float z = 0.f;
            for (int J = 0; J <= Ir; ++J){
                #pragma unroll
                for (int j = 0; j < 16; ++j) z += P[eidx(Ir,J,j,rb)]*gsp[J*16+j];
            }
            zp[t] = z;
        }
        __syncthreads();
        // u_c = (X^T z)_c = sum_{I>=J0} S_IJ0 row j0 . z[16I..]
        {
            float u = 0.f;
            for (int I = J0; I < 16; ++I){
                #pragma unroll
                for (int q = 0; q < 4; ++q){
                    float4 v = P4[f4idx(I,J0,j0,q)];
                    const float* zz = &zp[I*16 + 4*q];
                    u += v.x*zz[0] + v.y*zz[1] + v.z*zz[2] + v.w*zz[3];
                }
            }
            mu[b*256 + t] += LRATE*u;
        }
        // loss scalars
        rdp[t] = w2v*dsum;
        __syncthreads();
        for (int s = 128; s > 0; s >>= 1){ if (t < s) rdp[t] += rdp[t+s]; __syncthreads(); }
        float trval = rdp[0];
        __syncthreads();
        rdp[t] = 2.f*logf(dlog[t]);
        __syncthreads();
        for (int s = 128; s > 0; s >>= 1){ if (t < s) rdp[t] += rdp[t+s]; __syncthreads(); }
        if (t == 0){
            atomicAdd(slot_trace,  trval - 256.f);            // trace(invK * (-A^-1))
            atomicAdd(slot_logabs, -logdetKp[0] - rdp[0]);    // logdet(invK) - logdet(A)
        }
    }
}

// ---------------- invK = X^T X as block-SYRK over transposed-stored X ----------------
// invK block (I,J) = sum_{R>=I} S_RI * S_RJ^T   (S_RJ[a][b] = X[16R+b][16J+a])
__global__ __launch_bounds__(256) void k_syrk(const float* __restrict__ S,
                                              float* __restrict__ invK,
                                              float* __restrict__ invKb){
    int sidx = blockIdx.x;   // 136 slots
    int I = (int)floorf((sqrtf(8.f*(float)sidx + 1.f) - 1.f)*0.5f);
    while (((I+1)*(I+2))>>1 <= sidx) ++I;
    while ((I*(I+1))>>1 > sidx) --I;
    int J = sidx - ((I*(I+1))>>1);
    int t = threadIdx.x; int i = t>>4, j = t&15;
    __shared__ float4 sA[64], sB[64];
    const float4* S4 = (const float4*)S;
    float s = 0.f;
    for (int R = I; R < 16; ++R){
        __syncthreads();
        if (t < 64) sA[t] = S4[bslot(R,I)*65 + t];
        else if (t < 128) sB[t-64] = S4[bslot(R,J)*65 + t-64];
        __syncthreads();
        #pragma unroll
        for (int q = 0; q < 4; ++q){
            float4 a = sA[i*4 + ((q + (i>>2))&3)];
            float4 c = sB[j*4 + ((q + (j>>2))&3)];
            s += a.x*c.x + a.y*c.y + a.z*c.z + a.w*c.w;
        }
    }
    int gi = I*16 + i, gj = J*16 + j;
    invK[(size_t)gi*256 + gj] = s;
    invK[(size_t)gj*256 + gi] = s;
    invKb[eidx(I,J,i,j)] = s;
}

// ---------------- lambda (+ optional loss pieces) ----------------
__global__ __launch_bounds__(256) void k_lambda(const float* __restrict__ W, const float* __restrict__ mu,
                                                const float* __restrict__ diagAinv, const float* __restrict__ Y,
                                                const float* __restrict__ bias_p, float* __restrict__ lambd,
                                                int iter0, int do_loss, float* __restrict__ scal){
    int b = blockIdx.x; int m = b / NNEUR; int t = threadIdx.x;
    __shared__ float r1[256], r2[256];
    float bias = bias_p[0];
    float ll = bias, q = 0.f;
    #pragma unroll
    for (int l = 0; l < NLAT; ++l){
        float w   = W[(((size_t)b)*NLAT + l)*NTT + t];
        float muv = mu[((size_t)(m*NLAT + l))*NTT + t];
        float dh  = iter0 ? (1.0f + JITTER) : (-diagAinv[((size_t)(m*NLAT + l))*NTT + t]);
        ll += w * muv;
        q  += w * w * dh;
    }
    float lam = expf(ll + 0.5f*q);
    size_t idx = (size_t)b*NTT + t;
    lambd[idx] = lam;
    if (do_loss){
        r1[t] = Y[idx]*ll; r2[t] = lam;
        __syncthreads();
        for (int s = 128; s > 0; s >>= 1){ if (t < s){ r1[t]+=r1[t+s]; r2[t]+=r2[t+s]; } __syncthreads(); }
        if (t == 0){ atomicAdd(&scal[0], r1[0]); atomicAdd(&scal[1], r2[0]); }
    }
}

// ---------------- grad, w2l (+ optional muK.mu loss piece) ----------------
__global__ __launch_bounds__(256) void k_grad(const float* __restrict__ W, const float* __restrict__ Y,
                                              const float* __restrict__ lambd, const float* __restrict__ mu,
                                              const float* __restrict__ invK, float* __restrict__ grad,
                                              float* __restrict__ w2l, int do_loss, float* __restrict__ scal){
    int b = blockIdx.x; int m = b >> 3; int l = b & 7; int t = threadIdx.x;
    __shared__ float mus[256];
    __shared__ float red[256];
    mus[t] = mu[(size_t)b*NTT + t];
    __syncthreads();
    float mk = 0.f;
    for (int u = 0; u < 256; ++u) mk += mus[u] * invK[(size_t)u*256 + t];
    float g = 0.f, w2a = 0.f;
    for (int n = 0; n < NNEUR; ++n){
        size_t wi = (((size_t)(m*NNEUR + n))*NLAT + l)*NTT + t;
        size_t yi = ((size_t)(m*NNEUR + n))*NTT + t;
        float w = W[wi]; float lam = lambd[yi];
        g   += w * (Y[yi] - lam);
        w2a += w * w * lam;
    }
    grad[(size_t)b*NTT + t] = g - mk;
    w2l [(size_t)b*NTT + t] = w2a;
    if (do_loss){
        red[t] = mk * mus[t];
        __syncthreads();
        for (int s = 128; s > 0; s >>= 1){ if (t < s) red[t] += red[t+s]; __syncthreads(); }
        if (t == 0) atomicAdd(&scal[2], red[0]);
    }
}

__global__ void k_loss(const float* __restrict__ scal, float* __restrict__ out_loss){
    // loss = sum(Y*ll) - sum(lam) - 0.5*muKmu - 0.5*trace + 0.5*logabs - nt
    out_loss[0] = scal[0] - scal[1] - 0.5f*scal[2] - 0.5f*scal[8+3] + 0.5f*scal[24+3] - 256.f;
}

__global__ void k_gather(const float* __restrict__ mu, const float* __restrict__ lambd, float* __restrict__ out){
    int idx = blockIdx.x*256 + threadIdx.x;
    if (idx < 16384) out[idx] = mu[idx];
    else if (idx < 16384 + 204800) out[idx] = lambd[idx - 16384];
}

extern "C" void kernel_launch(void* const* d_in, const int* in_sizes, int n_in,
                              void* d_out, int out_size, void* d_ws, size_t ws_size,
                              hipStream_t stream){
    (void)in_sizes; (void)n_in; (void)out_size; (void)ws_size;
    const float* Y       = (const float*)d_in[0];
    const float* raw     = (const float*)d_in[1];
    const float* kern    = (const float*)d_in[2];
    const float* readout = (const float*)d_in[3];
    const float* K       = (const float*)d_in[4];
    const float* bias    = (const float*)d_in[5];
    float* out = (float*)d_out;
    float* ws  = (float*)d_ws;

    float* invK   = ws;                        // 65536
    float* invKb  = invK + 65536;              // 35360 (blocked)
    float* Sblk   = invKb + NBLKF;             // 35360 (blocked X^T of K')
    float* W      = Sblk + NBLKF;              // 1,638,400
    float* mu     = W + 1638400;               // 16384
    float* lambd  = mu + 16384;                // 204800
    float* grad   = lambd + 204800;            // 16384
    float* w2l    = grad + 16384;              // 16384
    float* diag   = w2l + 16384;               // 16384
    float* scal   = diag + 16384;              // 64: [0]=ylog [1]=lamsum [2]=muKmu [8+i]=trace_i [20]=logdetKp [24+i]=logabs_i
    float* kt     = scal + 64;                 // 500,000

    k_zero<<<64, 256, 0, stream>>>(mu, scal);
    k_transpose<<<(NNEUR*NTAU*NNEUR + 255)/256, 256, 0, stream>>>(kern, kt);
    k_conv_weights<<<NTRIAL*NNEUR, 256, 0, stream>>>(raw, kt, readout, W);

    // one-time: X = chol(K')^-1 (blocked, transposed store), logdet(K'); then invK = X^T X
    k_fact<0><<<1, 256, 0, stream>>>(K, nullptr, nullptr, nullptr, nullptr, nullptr,
                                     Sblk, scal + 20, nullptr, nullptr);
    k_syrk<<<NSLOT, 256, 0, stream>>>(Sblk, invK, invKb);

    for (int it = 0; it < 5; ++it){
        int first = (it == 0) ? 1 : 0;
        int last  = (it == 4) ? 1 : 0;
        k_lambda<<<NTRIAL*NNEUR, 256, 0, stream>>>(W, mu, diag, Y, bias, lambd, first, last, scal);
        k_grad<<<NMAT, 256, 0, stream>>>(W, Y, lambd, mu, invK, grad, w2l, last, scal);
        k_fact<1><<<NMAT, 256, 0, stream>>>(nullptr, invKb, w2l, grad, mu, diag,
                                            nullptr, scal + 20, scal + 8 + it, scal + 24 + it);
    }
    k_loss<<<1, 1, 0, stream>>>(scal, out + 16384 + 204800);
    k_gather<<<864, 256, 0, stream>>>(mu, lambd, out);
}

// Round 4
// 1537.155 us; speedup vs baseline: 14.5450x; 1.3021x over previous
//
#include <hip/hip_runtime.h>

#define NTRIAL 8
#define NNEUR 100
#define NTT 256
#define NT_FULL 300
#define NTAU 50
#define NLAT 8
#define NPAD 44
#define LRATE 0.2f
#define JITTER 0.001f
#define NMAT 64            // NTRIAL*NLAT batched 256x256 matrices
#define NSLOT 136          // 16*17/2 lower 16x16 blocks
#define SPITCH 260         // floats per block slot
#define NBLKF 35360        // NSLOT*SPITCH
#define NBLKF4 8840        // float4 count

__device__ __forceinline__ int bslot(int I, int J){ return ((I*(I+1))>>1) + J; }
__device__ __forceinline__ int eidx(int I, int J, int i, int j){
    return bslot(I,J)*SPITCH + i*16 + ((((j>>2) + (i>>2))&3)<<2) + (j&3);
}
__device__ __forceinline__ int f4idx(int I, int J, int i, int q){
    return bslot(I,J)*65 + i*4 + ((q + (i>>2))&3);
}
__device__ __forceinline__ int bsidx(int J, int k, int col){
    return J*260 + k*16 + ((((col>>2) + (k>>2))&3)<<2) + (col&3);
}
#define DOT4(u,v) (u.x*v.x + u.y*v.y + u.z*v.z + u.w*v.w)

// acc += rows(ti..ti+3) of slot baseA  .  rows(tj..tj+3) of slot baseB (16-wide dot)
__device__ __forceinline__ void gemm16(const float4* P4, int baseA, int baseB,
                                       int ti, int tj, float acc[4][4]){
    #pragma unroll
    for (int kc = 0; kc < 4; ++kc){
        float4 a0 = P4[baseA + (ti+0)*4 + ((kc + ((ti+0)>>2))&3)];
        float4 a1 = P4[baseA + (ti+1)*4 + ((kc + ((ti+1)>>2))&3)];
        float4 a2 = P4[baseA + (ti+2)*4 + ((kc + ((ti+2)>>2))&3)];
        float4 a3 = P4[baseA + (ti+3)*4 + ((kc + ((ti+3)>>2))&3)];
        float4 b0 = P4[baseB + (tj+0)*4 + ((kc + ((tj+0)>>2))&3)];
        float4 b1 = P4[baseB + (tj+1)*4 + ((kc + ((tj+1)>>2))&3)];
        float4 b2 = P4[baseB + (tj+2)*4 + ((kc + ((tj+2)>>2))&3)];
        float4 b3 = P4[baseB + (tj+3)*4 + ((kc + ((tj+3)>>2))&3)];
        acc[0][0]+=DOT4(a0,b0); acc[0][1]+=DOT4(a0,b1); acc[0][2]+=DOT4(a0,b2); acc[0][3]+=DOT4(a0,b3);
        acc[1][0]+=DOT4(a1,b0); acc[1][1]+=DOT4(a1,b1); acc[1][2]+=DOT4(a1,b2); acc[1][3]+=DOT4(a1,b3);
        acc[2][0]+=DOT4(a2,b0); acc[2][1]+=DOT4(a2,b1); acc[2][2]+=DOT4(a2,b2); acc[2][3]+=DOT4(a2,b3);
        acc[3][0]+=DOT4(a3,b0); acc[3][1]+=DOT4(a3,b1); acc[3][2]+=DOT4(a3,b2); acc[3][3]+=DOT4(a3,b3);
    }
}

// ---------------- init ----------------
__global__ void k_zero(float* mu, float* scal){
    int i = blockIdx.x*256 + threadIdx.x;
    if (i < 16384) mu[i] = 0.f;
    if (i < 64) scal[i] = 0.f;
}

__global__ void k_transpose(const float* __restrict__ kern, float* __restrict__ kt){
    int idx = blockIdx.x*256 + threadIdx.x;
    if (idx >= NNEUR*NTAU*NNEUR) return;
    int i = idx/(NTAU*NNEUR); int rem = idx%(NTAU*NNEUR);
    int tau = rem/NNEUR; int j = rem%NNEUR;
    kt[((size_t)i*NNEUR + j)*NTAU + tau] = kern[idx];
}

// ---------------- conv + readout contraction ----------------
__global__ __launch_bounds__(256) void k_conv_weights(const float* __restrict__ raw,
                                                      const float* __restrict__ kt,
                                                      const float* __restrict__ readout,
                                                      float* __restrict__ W){
    int b = blockIdx.x; int m = b / NNEUR; int j = b % NNEUR; int t = threadIdx.x;
    __shared__ float ro[NNEUR*NLAT];
    __shared__ float raw_s[10][NT_FULL];
    __shared__ float kern_s[10][NTAU];
    for (int idx = t; idx < NNEUR*NLAT; idx += 256) ro[idx] = readout[idx];
    float acc[NLAT];
    #pragma unroll
    for (int l = 0; l < NLAT; ++l) acc[l] = 0.f;
    int tmax = min(NTAU, t + NPAD);
    for (int c = 0; c < 10; ++c){
        __syncthreads();
        for (int idx = t; idx < 10*NT_FULL; idx += 256){
            int ii = idx / NT_FULL, tt = idx % NT_FULL;
            raw_s[ii][tt] = raw[((size_t)m*NNEUR + c*10 + ii)*NT_FULL + tt];
        }
        for (int idx = t; idx < 10*NTAU; idx += 256){
            int ii = idx / NTAU, tau = idx % NTAU;
            kern_s[ii][tau] = kt[((size_t)(c*10 + ii)*NNEUR + j)*NTAU + tau];
        }
        __syncthreads();
        for (int ii = 0; ii < 10; ++ii){
            float g = 0.f;
            const float* kr = kern_s[ii];
            const float* rr = raw_s[ii];
            for (int tau = 1; tau <= tmax; ++tau) g += kr[tau-1] * rr[t + NPAD - tau];
            if (fabsf(g) < 1e-5f) g = 0.f;   // ZERO_THRESH before readout contraction
            const float* rop = &ro[(c*10 + ii)*NLAT];
            #pragma unroll
            for (int l = 0; l < NLAT; ++l) acc[l] += rop[l]*g;
        }
    }
    #pragma unroll
    for (int l = 0; l < NLAT; ++l) W[(((size_t)b)*NLAT + l)*NTT + t] = acc[l];
}

// ============ fused: (lambda+grad) + blocked chol + in-place blocked trinv + solve ============
// MODE 0: 1 block. In Kin+jitter. Out Sblk (blocked X^T), scal[20]=logdet(K').
// MODE 1: NMAT blocks. Fuses lambda/grad/w2l/mk, then A = invK + diag(w2l) fact,
//         diagOut, muOut = muIn + LR*A^-1 grad, loss atomics.
template<int MODE>
__global__ __launch_bounds__(512) void k_fact(
    const float* __restrict__ Kin,
    const float* __restrict__ invKb,
    const float* __restrict__ W,
    const float* __restrict__ Y,
    const float* __restrict__ bias_p,
    const float* __restrict__ muIn,
    const float* __restrict__ diagIn,
    float* __restrict__ muOut,
    float* __restrict__ diagOut,
    float* __restrict__ lambd,
    float* __restrict__ Sout,
    float* __restrict__ scal,
    int it0, int it4, int itSlot)
{
    __shared__ float4 P4[NBLKF4];      // 141,440 B blocked lower-tri matrix
    __shared__ float4 Bs4[1040];       //  16,640 B scratch (partials / trinv B / zp)
    __shared__ float dlog[256];        // chol diag (overlay: muown pre-chol)
    __shared__ float idg[16];
    __shared__ float extra[1024];      // gs[0:256) w2ls[256:512) red[512:1024)
    float* P    = (float*)P4;
    float* Bsf  = (float*)Bs4;
    float* gs   = extra;
    float* w2ls = extra + 256;
    float* red  = extra + 512;
    float* muown = dlog;
    const int t = threadIdx.x;
    const int b = blockIdx.x;
    const int g = t>>4, gt = t&15;
    const int ti = (gt>>2)<<2, tj = (gt&3)<<2;
    const int lanebase = t & 48;       // within-wave base lane of this 16-group

    // ---------------- prologue ----------------
    if (MODE == 0){
        if (t < 256){
            int r = t, I = r>>4, i = r&15;
            for (int c = 0; c <= r; ++c)
                P[eidx(I, c>>4, i, c&15)] = Kin[r*256 + c] + ((c==r)?JITTER:0.f);
        }
        __syncthreads();
    } else {
        const int m_ = b >> 3, l_ = b & 7;
        const float4* G4 = (const float4*)invKb;
        for (int e = t; e < NBLKF4; e += 512) P4[e] = G4[e];
        const int t2 = t & 255, half = t >> 8;
        float mul[NLAT], dhl[NLAT];
        #pragma unroll
        for (int l = 0; l < NLAT; ++l){
            mul[l] = muIn[((size_t)(m_*NLAT + l))*NTT + t2];
            dhl[l] = it0 ? (1.0f + JITTER) : (-diagIn[((size_t)(m_*NLAT + l))*NTT + t2]);
        }
        if (t < 256) muown[t] = mul[l_];
        float bias = bias_p[0];
        float gacc = 0.f, w2acc = 0.f, yl = 0.f, ls = 0.f;
        for (int n = half*50; n < half*50 + 50; ++n){
            size_t base = (((size_t)(m_*NNEUR + n))*NLAT)*NTT + t2;
            float wl[NLAT];
            float ll = bias, q = 0.f;
            #pragma unroll
            for (int l = 0; l < NLAT; ++l){
                float w = W[base + (size_t)l*NTT];
                wl[l] = w;
                ll += w * mul[l];
                q  += w * w * dhl[l];
            }
            float lam = expf(ll + 0.5f*q);
            float yv = Y[((size_t)(m_*NNEUR + n))*NTT + t2];
            float wo = wl[l_];
            gacc  += wo * (yv - lam);
            w2acc += wo * wo * lam;
            if (it4){
                lambd[((size_t)(m_*NNEUR + n))*NTT + t2] = lam;
                yl += yv * ll; ls += lam;
            }
        }
        Bsf[half*256 + t2]       = gacc;
        Bsf[512 + half*256 + t2] = w2acc;
        __syncthreads();
        if (it4){
            red[t] = yl;
            __syncthreads();
            for (int s = 256; s > 0; s >>= 1){ if (t < s) red[t] += red[t+s]; __syncthreads(); }
            if (t == 0 && l_ == 0) atomicAdd(&scal[0], red[0]);
            __syncthreads();
            red[t] = ls;
            __syncthreads();
            for (int s = 256; s > 0; s >>= 1){ if (t < s) red[t] += red[t+s]; __syncthreads(); }
            if (t == 0 && l_ == 0) atomicAdd(&scal[1], red[0]);
            __syncthreads();
        }
        if (t < 256){
            float gg = Bsf[t] + Bsf[256 + t];
            float w2 = Bsf[512 + t] + Bsf[768 + t];
            int T = t>>4, tb = t&15;
            float mk = 0.f;
            for (int U = 0; U < 16; ++U){
                if (U <= T){
                    #pragma unroll
                    for (int u = 0; u < 16; ++u) mk += muown[U*16+u] * P[eidx(T,U,tb,u)];
                } else {
                    #pragma unroll
                    for (int u = 0; u < 16; ++u) mk += muown[U*16+u] * P[eidx(U,T,u,tb)];
                }
            }
            gs[t]   = gg - mk;
            w2ls[t] = w2;
            red[t]  = mk * muown[t];
        } else red[t] = 0.f;
        if (it4){
            __syncthreads();
            for (int s = 256; s > 0; s >>= 1){ if (t < s) red[t] += red[t+s]; __syncthreads(); }
            if (t == 0) atomicAdd(&scal[2], red[0]);
        }
        __syncthreads();                    // all mk reads of P done
        if (t < 256) P[eidx(t>>4, t>>4, t&15, t&15)] += w2ls[t];
        __syncthreads();
    }

    // ---------------- blocked Cholesky (micro-chol hidden on group 31) ----------------
    for (int p = 0; p < 16; ++p){
        const int pm = p - 1;
        if (g == 31){
            float x[16];
            if (p > 0){
                float acc[4][4];
                #pragma unroll
                for (int aa=0;aa<4;++aa){acc[aa][0]=0;acc[aa][1]=0;acc[aa][2]=0;acc[aa][3]=0;}
                gemm16(P4, bslot(p,pm)*65, bslot(p,pm)*65, ti, tj, acc);
                #pragma unroll
                for (int aa = 0; aa < 4; ++aa){
                    int oi = f4idx(p,p,ti+aa,tj>>2);
                    float4 c = P4[oi];
                    c.x-=acc[aa][0]; c.y-=acc[aa][1]; c.z-=acc[aa][2]; c.w-=acc[aa][3];
                    P4[oi] = c;
                }
            }
            #pragma unroll
            for (int q = 0; q < 4; ++q){
                float4 v = P4[f4idx(p,p,gt,q)];
                x[4*q]=v.x; x[4*q+1]=v.y; x[4*q+2]=v.z; x[4*q+3]=v.w;
            }
            const int i = gt;
            #pragma unroll
            for (int k = 0; k < 16; ++k){
                float piv = __shfl(x[k], lanebase + k, 64);
                float d = sqrtf(piv);
                float dinv = 1.f/d;
                float lik = (i == k) ? d : x[k]*dinv;
                if (i >= k) x[k] = lik;
                #pragma unroll
                for (int c = k+1; c < 16; ++c){
                    float lck = __shfl(x[k], lanebase + c, 64);
                    if (i >= c) x[c] -= lik*lck;
                }
                if (i == k){ idg[k] = dinv; dlog[p*16+k] = d; }
            }
            #pragma unroll
            for (int q = 0; q < 4; ++q)
                P4[f4idx(p,p,i,q)] = make_float4(x[4*q],x[4*q+1],x[4*q+2],x[4*q+3]);
        } else if (p > 0 && g < 28){
            int m = 16 - p;
            int npairs = (m*(m+1))>>1;
            for (int q = 1+g; q < npairs; q += 28){
                int di = (int)floorf((sqrtf(8.f*(float)q + 1.f) - 1.f)*0.5f);
                while (((di+1)*(di+2))>>1 <= q) ++di;
                while ((di*(di+1))>>1 > q) --di;
                int dj = q - ((di*(di+1))>>1);
                int I = p+di, J = p+dj;
                float acc[4][4];
                #pragma unroll
                for (int aa=0;aa<4;++aa){acc[aa][0]=0;acc[aa][1]=0;acc[aa][2]=0;acc[aa][3]=0;}
                gemm16(P4, bslot(I,pm)*65, bslot(J,pm)*65, ti, tj, acc);
                #pragma unroll
                for (int aa = 0; aa < 4; ++aa){
                    int oi = f4idx(I,J,ti+aa,tj>>2);
                    float4 c = P4[oi];
                    c.x-=acc[aa][0]; c.y-=acc[aa][1]; c.z-=acc[aa][2]; c.w-=acc[aa][3];
                    P4[oi] = c;
                }
            }
        }
        __syncthreads();
        if (p < 15){
            int nrows = (15 - p)*16;
            if (t < nrows){
                int r = (p+1)*16 + t;
                int I = r>>4, i = r&15;
                float x[16];
                #pragma unroll
                for (int q = 0; q < 4; ++q){
                    float4 v = P4[f4idx(I,p,i,q)];
                    x[4*q]=v.x; x[4*q+1]=v.y; x[4*q+2]=v.z; x[4*q+3]=v.w;
                }
                #pragma unroll
                for (int c = 0; c < 16; ++c){
                    float s = x[c];
                    #pragma unroll
                    for (int j = 0; j < c; ++j) s -= x[j]*P[eidx(p,p,c,j)];
                    x[c] = s*idg[c];
                }
                #pragma unroll
                for (int q = 0; q < 4; ++q)
                    P4[f4idx(I,p,i,q)] = make_float4(x[4*q],x[4*q+1],x[4*q+2],x[4*q+3]);
            }
        }
        __syncthreads();
    }

    // ---------------- blocked in-place trinv (transposed store), micro-inv on group 31 ----------------
    for (int I = 0; I < 16; ++I){
        if (g == 31){
            const int j = gt;
            float col[16];
            #pragma unroll
            for (int k=0;k<16;++k) col[k] = 0.f;
            #pragma unroll
            for (int i = 0; i < 16; ++i){
                float Lii = P[eidx(I,I,i,i)];
                float s = 0.f;
                #pragma unroll
                for (int k = 0; k < 16; ++k){
                    if (k < i){ float term = P[eidx(I,I,i,k)]*col[k]; s += (k >= j) ? term : 0.f; }
                }
                col[i] = (i == j) ? (1.f/Lii) : ((i > j) ? (-s/Lii) : 0.f);
            }
            #pragma unroll
            for (int q = 0; q < 4; ++q)
                P4[f4idx(I,I,j,q)] = make_float4(col[4*q],col[4*q+1],col[4*q+2],col[4*q+3]);
        } else {
            int pj = g>>1, half = g&1;
            if (pj < I){
                const int J = pj;
                float acc[4][4];
                #pragma unroll
                for (int aa=0;aa<4;++aa){acc[aa][0]=0;acc[aa][1]=0;acc[aa][2]=0;acc[aa][3]=0;}
                for (int K = J+half; K < I; K += 2)
                    gemm16(P4, bslot(I,K)*65, bslot(K,J)*65, ti, tj, acc);
                #pragma unroll
                for (int aa = 0; aa < 4; ++aa){
                    #pragma unroll
                    for (int bb = 0; bb < 4; ++bb)
                        acc[aa][bb] += __shfl_xor(acc[aa][bb], 16, 64);
                }
                if (half == 0){
                    #pragma unroll
                    for (int aa = 0; aa < 4; ++aa)
                        Bs4[J*65 + (ti+aa)*4 + (((tj>>2)+((ti+aa)>>2))&3)] =
                            make_float4(acc[aa][0],acc[aa][1],acc[aa][2],acc[aa][3]);
                }
            }
        }
        __syncthreads();
        {
            int pj = g>>1;
            if (pj < I && g < 31){
                const int J = pj;
                const int u = ((g&1)<<4) | gt;
                const int ti2 = ((u>>3)&3)<<2;
                const int tjb = (u&7)<<1;
                float acc2[4][2];
                acc2[0][0]=0;acc2[0][1]=0;acc2[1][0]=0;acc2[1][1]=0;
                acc2[2][0]=0;acc2[2][1]=0;acc2[3][0]=0;acc2[3][1]=0;
                #pragma unroll
                for (int k = 0; k < 16; ++k){
                    float4 sa = P4[f4idx(I,I,k,ti2>>2)];
                    float b0 = Bsf[bsidx(J,k,tjb)];
                    float b1 = Bsf[bsidx(J,k,tjb+1)];
                    acc2[0][0]+=sa.x*b0; acc2[0][1]+=sa.x*b1;
                    acc2[1][0]+=sa.y*b0; acc2[1][1]+=sa.y*b1;
                    acc2[2][0]+=sa.z*b0; acc2[2][1]+=sa.z*b1;
                    acc2[3][0]+=sa.w*b0; acc2[3][1]+=sa.w*b1;
                }
                #pragma unroll
                for (int bb = 0; bb < 2; ++bb)
                    P4[f4idx(I,J,tjb+bb,ti2>>2)] =
                        make_float4(-acc2[0][bb],-acc2[1][bb],-acc2[2][bb],-acc2[3][bb]);
            }
        }
        __syncthreads();
    }

    // ---------------- epilogue ----------------
    if (MODE == 0){
        red[t] = (t < 256) ? 2.f*logf(dlog[t]) : 0.f;
        __syncthreads();
        for (int s = 256; s > 0; s >>= 1){ if (t < s) red[t] += red[t+s]; __syncthreads(); }
        if (t == 0) scal[20] = red[0];
        float4* SO = (float4*)Sout;
        for (int e = t; e < NBLKF4; e += 512) SO[e] = P4[e];
        return;
    } else {
        float* zp = Bsf;                   // Bs free now
        float dsum = 0.f;
        if (t < 256){
            const int J0 = t>>4, j0 = t&15;
            for (int I = J0; I < 16; ++I){
                #pragma unroll
                for (int q = 0; q < 4; ++q){
                    float4 v = P4[f4idx(I,J0,j0,q)];
                    dsum += v.x*v.x + v.y*v.y + v.z*v.z + v.w*v.w;
                }
            }
            diagOut[b*256 + t] = dsum;
            const int Ir = t>>4, rb = t&15;
            float z = 0.f;
            for (int J = 0; J <= Ir; ++J){
                #pragma unroll
                for (int j = 0; j < 16; ++j) z += P[eidx(Ir,J,j,rb)]*gs[J*16+j];
            }
            zp[t] = z;
        }
        __syncthreads();
        if (t < 256){
            const int J0 = t>>4, j0 = t&15;
            float u = 0.f;
            for (int I = J0; I < 16; ++I){
                #pragma unroll
                for (int q = 0; q < 4; ++q){
                    float4 v = P4[f4idx(I,J0,j0,q)];
                    const float* zz = &zp[I*16 + 4*q];
                    u += v.x*zz[0] + v.y*zz[1] + v.z*zz[2] + v.w*zz[3];
                }
            }
            muOut[b*256 + t] = muIn[b*256 + t] + LRATE*u;
            red[t]       = w2ls[t]*dsum;
            red[256 + t] = 2.f*logf(dlog[t]);
        }
        __syncthreads();
        for (int s = 128; s > 0; s >>= 1){
            if (t < s){ red[t] += red[t+s]; red[256+t] += red[256+t+s]; }
            __syncthreads();
        }
        if (t == 0){
            atomicAdd(&scal[8 + itSlot],  red[0] - 256.f);          // trace(invK * -A^-1)
            atomicAdd(&scal[24 + itSlot], -scal[20] - red[256]);    // logdet(invK) - logdet(A)
        }
    }
}

// ---------------- invKb = X^T X (blocked) ----------------
__global__ __launch_bounds__(256) void k_syrk(const float* __restrict__ S,
                                              float* __restrict__ invKb){
    int sidx = blockIdx.x;
    int I = (int)floorf((sqrtf(8.f*(float)sidx + 1.f) - 1.f)*0.5f);
    while (((I+1)*(I+2))>>1 <= sidx) ++I;
    while ((I*(I+1))>>1 > sidx) --I;
    int J = sidx - ((I*(I+1))>>1);
    int t = threadIdx.x; int i = t>>4, j = t&15;
    __shared__ float4 sA[64], sB[64];
    const float4* S4 = (const float4*)S;
    float s = 0.f;
    for (int R = I; R < 16; ++R){
        __syncthreads();
        if (t < 64) sA[t] = S4[bslot(R,I)*65 + t];
        else if (t < 128) sB[t-64] = S4[bslot(R,J)*65 + t-64];
        __syncthreads();
        #pragma unroll
        for (int q = 0; q < 4; ++q){
            float4 a = sA[i*4 + ((q + (i>>2))&3)];
            float4 c = sB[j*4 + ((q + (j>>2))&3)];
            s += a.x*c.x + a.y*c.y + a.z*c.z + a.w*c.w;
        }
    }
    invKb[eidx(I,J,i,j)] = s;
}

__global__ void k_loss(const float* __restrict__ scal, float* __restrict__ out_loss){
    out_loss[0] = scal[0] - scal[1] - 0.5f*scal[2] - 0.5f*scal[8+3] + 0.5f*scal[24+3] - 256.f;
}

__global__ void k_gather(const float* __restrict__ mu, const float* __restrict__ lambd, float* __restrict__ out){
    int idx = blockIdx.x*256 + threadIdx.x;
    if (idx < 16384) out[idx] = mu[idx];
    else if (idx < 16384 + 204800) out[idx] = lambd[idx - 16384];
}

extern "C" void kernel_launch(void* const* d_in, const int* in_sizes, int n_in,
                              void* d_out, int out_size, void* d_ws, size_t ws_size,
                              hipStream_t stream){
    (void)in_sizes; (void)n_in; (void)out_size; (void)ws_size;
    const float* Y       = (const float*)d_in[0];
    const float* raw     = (const float*)d_in[1];
    const float* kern    = (const float*)d_in[2];
    const float* readout = (const float*)d_in[3];
    const float* K       = (const float*)d_in[4];
    const float* bias    = (const float*)d_in[5];
    float* out = (float*)d_out;
    float* ws  = (float*)d_ws;

    float* invKb  = ws;                        // 35360 blocked invK
    float* Sblk   = invKb + NBLKF;             // 35360 blocked X^T of K'
    float* W      = Sblk + NBLKF;              // 1,638,400
    float* muA    = W + 1638400;               // 16384
    float* muB    = muA + 16384;               // 16384
    float* lambd  = muB + 16384;               // 204800
    float* diagA  = lambd + 204800;            // 16384
    float* diagB  = diagA + 16384;             // 16384
    float* scal   = diagB + 16384;             // 64: [0]=ylog [1]=lamsum [2]=muKmu [8+i]=trace_i [20]=logdetKp [24+i]=logabs_i
    float* kt     = scal + 64;                 // 500,000

    k_zero<<<64, 256, 0, stream>>>(muA, scal);
    k_transpose<<<(NNEUR*NTAU*NNEUR + 255)/256, 256, 0, stream>>>(kern, kt);
    k_conv_weights<<<NTRIAL*NNEUR, 256, 0, stream>>>(raw, kt, readout, W);

    // one-time: X = chol(K')^-1 blocked/transposed, logdet(K'); then invKb = X^T X
    k_fact<0><<<1, 512, 0, stream>>>(K, nullptr, nullptr, nullptr, nullptr, nullptr, nullptr,
                                     nullptr, nullptr, nullptr, Sblk, scal, 0, 0, 0);
    k_syrk<<<NSLOT, 256, 0, stream>>>(Sblk, invKb);

    for (int it = 0; it < 5; ++it){
        const float* muI = (it & 1) ? muB : muA;
        float*       muO = (it & 1) ? muA : muB;
        const float* dI  = (it & 1) ? diagB : diagA;
        float*       dO  = (it & 1) ? diagA : diagB;
        k_fact<1><<<NMAT, 512, 0, stream>>>(nullptr, invKb, W, Y, bias, muI, dI,
                                            muO, dO, lambd, nullptr, scal,
                                            (it == 0) ? 1 : 0, (it == 4) ? 1 : 0, it);
    }
    k_loss<<<1, 1, 0, stream>>>(scal, out + 16384 + 204800);
    k_gather<<<864, 256, 0, stream>>>(muB, lambd, out);
}